// Round 11
// baseline (175.332 us; speedup 1.0000x reference)
//
#include <hip/hip_runtime.h>

#define NP   8192
#define BB   4
#define DIN  32
#define M0   32
#define M1   32
#define M2   64
#define CAP  80
#define CSTR 81            // candidate row stride (odd -> conflict-free)
#define KQ   32            // queries per knn block

typedef float f32x2 __attribute__((ext_vector_type(2)));
typedef float f32x4 __attribute__((ext_vector_type(4)));
typedef short bf16x8 __attribute__((ext_vector_type(8)));

__device__ __forceinline__ float lrelu(float x) { return fmaxf(x, 0.1f * x); }
__device__ __forceinline__ unsigned umin_(unsigned a, unsigned b) { return a < b ? a : b; }
__device__ __forceinline__ unsigned umax_(unsigned a, unsigned b) { return a > b ? a : b; }

// monotonic float->uint key (total order incl. negatives)
__device__ __forceinline__ unsigned fkey(float f) {
    unsigned b = __float_as_uint(f);
    return (b & 0x80000000u) ? ~b : (b | 0x80000000u);
}
__device__ __forceinline__ float funkey(unsigned k) {
    unsigned b = (k & 0x80000000u) ? (k & 0x7fffffffu) : ~k;
    return __uint_as_float(b);
}

// round-to-nearest-even f32 -> bf16 (as uint16 in low bits)
__device__ __forceinline__ unsigned bf16rn(float f) {
    unsigned u = __float_as_uint(f);
    unsigned r = (u >> 16) & 1u;
    return (u + 0x7fffu + r) >> 16;
}

// packed f32 FMA (knn): d = a*b + c per half; b wave-uniform -> SGPR pair.
__device__ __forceinline__ f32x2 pk_fma(f32x2 a, f32x2 b, f32x2 c) {
    f32x2 d;
    asm("v_pk_fma_f32 %0, %1, %2, %3" : "=v"(d) : "v"(a), "s"(b), "v"(c));
    return d;
}

// exact lane^j exchange, cheapest primitive per stride. All three forms are
// already proven in this kernel (conv: DPP 0xB1/0x4E, ds_swizzle 0x401F).
// j folds to a constant under full unroll -> each case uses a literal pattern.
__device__ __forceinline__ unsigned xorswap(unsigned v, int j) {
    switch (j) {
    case 1:  return (unsigned)__builtin_amdgcn_update_dpp(0, (int)v, 0xB1, 0xf, 0xf, true); // quad xor1
    case 2:  return (unsigned)__builtin_amdgcn_update_dpp(0, (int)v, 0x4E, 0xf, 0xf, true); // quad xor2
    case 4:  return (unsigned)__builtin_amdgcn_ds_swizzle((int)v, 0x101F);  // BitMode xor4
    case 8:  return (unsigned)__builtin_amdgcn_ds_swizzle((int)v, 0x201F);  // BitMode xor8
    case 16: return (unsigned)__builtin_amdgcn_ds_swizzle((int)v, 0x401F);  // BitMode xor16
    default: return (unsigned)__shfl_xor((int)v, 32);                       // crosses 32-lane half
    }
}

// hi/lo bf16 split of a float pair, packed as two u32 (lo16|hi16 each).
__device__ __forceinline__ void split_pack2(float f0, float f1, unsigned& hp, unsigned& lp) {
    unsigned u0 = __float_as_uint(f0), u1 = __float_as_uint(f1);
    unsigned h0 = u0 & 0xffff0000u, h1 = u1 & 0xffff0000u;
    hp = (u0 >> 16) | h1;
    float r0 = f0 - __uint_as_float(h0);
    float r1 = f1 - __uint_as_float(h1);
    lp = (__float_as_uint(r0) >> 16) | (__float_as_uint(r1) & 0xffff0000u);
}

// Build hi/lo bf16 A/B-fragments from 8 consecutive f32 weights.
__device__ __forceinline__ void wfrag(const float* wrow, bf16x8& h, bf16x8& lo) {
    float4 a = *(const float4*)(wrow);
    float4 b = *(const float4*)(wrow + 4);
    unsigned* hv = (unsigned*)&h;
    unsigned* lv = (unsigned*)&lo;
    split_pack2(a.x, a.y, hv[0], lv[0]);
    split_pack2(a.z, a.w, hv[1], lv[1]);
    split_pack2(b.x, b.y, hv[2], lv[2]);
    split_pack2(b.z, b.w, hv[3], lv[3]);
}

__device__ __forceinline__ f32x4 mfma16(bf16x8 a, bf16x8 b, f32x4 c) {
    return __builtin_amdgcn_mfma_f32_16x16x32_bf16(a, b, c, 0, 0, 0);
}

// ---------------------------------------------------------------------------
// Kernel 1: pack pts4/ptsS + feat = W0[:,3:] @ points (bf16 pairs). Block 0
// additionally writes the per-lane W1/W2 hi/lo MFMA fragment tables.
// ---------------------------------------------------------------------------
__global__ __launch_bounds__(256) void prep_kernel(
    const float* __restrict__ xyz, const float* __restrict__ points,
    const float* __restrict__ W0, const float* __restrict__ W1,
    const float* __restrict__ W2, float4* __restrict__ pts4,
    float4* __restrict__ ptsS, unsigned* __restrict__ featb,
    uint4* __restrict__ w1f, uint4* __restrict__ w2f)
{
    const int tid  = threadIdx.x;
    const int w    = __builtin_amdgcn_readfirstlane(tid >> 6);  // 0..3
    const int lane = tid & 63;
    const int t    = blockIdx.x * 64 + lane;     // point id, 512 blocks
    const int b    = t >> 13;
    const int n    = t & (NP - 1);

    if (w == 0) {
        const float* xb = xyz + (size_t)b * 3 * NP;
        float x = xb[n], y = xb[NP + n], z = xb[2 * NP + n];
        float s = x * x + y * y + z * z;
        pts4[t] = make_float4(x, y, z, s);
        ptsS[t] = make_float4(-2.f * x, -2.f * y, -2.f * z, s);
    }

    const float* pb = points + (size_t)b * DIN * NP + n;
    float p[DIN];
#pragma unroll
    for (int c = 0; c < DIN; ++c) p[c] = pb[c * NP];

    uint4 outv;
    unsigned* ov = (unsigned*)&outv;
#pragma unroll
    for (int r = 0; r < 4; ++r) {
        int oe = w * 8 + 2 * r;
        float a0 = 0.f, a1 = 0.f;
#pragma unroll
        for (int c = 0; c < DIN; ++c) {
            a0 = fmaf(W0[oe * 35 + 3 + c], p[c], a0);
            a1 = fmaf(W0[(oe + 1) * 35 + 3 + c], p[c], a1);
        }
        ov[r] = bf16rn(a0) | (bf16rn(a1) << 16);
    }
    *(uint4*)(featb + (size_t)t * 16 + w * 4) = outv;

    // ---- one-time W fragment tables (lane l: q=l&15 spatial, g=l>>4 kgrp) ----
    if (blockIdx.x == 0 && tid < 64) {
        const int qq = tid & 15, gg = tid >> 4;
        bf16x8 h, lo;
#pragma unroll
        for (int r = 0; r < 2; ++r) {
            wfrag(W1 + (16 * r + qq) * 32 + gg * 8, h, lo);
            w1f[(r * 64 + tid) * 2 + 0] = *(uint4*)&h;
            w1f[(r * 64 + tid) * 2 + 1] = *(uint4*)&lo;
        }
#pragma unroll
        for (int rr = 0; rr < 4; ++rr) {
            wfrag(W2 + (16 * rr + qq) * 32 + gg * 8, h, lo);
            w2f[(rr * 64 + tid) * 2 + 0] = *(uint4*)&h;
            w2f[(rr * 64 + tid) * 2 + 1] = *(uint4*)&lo;
        }
    }
}

// ---------------------------------------------------------------------------
// Kernel 2: exact 16-NN — session-best structure (95.5 µs), with the sort
// phases' lane exchanges lowered to DPP / ds_swizzle / shfl per stride
// (identical exchange network -> bit-identical output). Everything else
// unchanged from the measured-best r10 kernel.
// ---------------------------------------------------------------------------
__global__ __launch_bounds__(512, 8) void knn_kernel(const float4* __restrict__ pts4,
                                                     const float4* __restrict__ ptsS,
                                                     int* __restrict__ idxout)
{
    __shared__ unsigned skey[KQ * 65];              // 8.3 KB class-min keys
    __shared__ float    sT[KQ];
    __shared__ int      scnt[KQ];
    __shared__ float    cand_t[KQ * CSTR];          // 10.4 KB
    __shared__ int      cand_i[KQ * CSTR];          // 10.4 KB

    const int tid  = threadIdx.x;
    const int w    = __builtin_amdgcn_readfirstlane(tid >> 6);   // 0..7
    const int lane = tid & 63;
    const int blk  = blockIdx.x;           // 1024 blocks
    const int b    = blk >> 8;
    const int n0   = (blk & 255) << 5;     // 32 queries per block
    const int bn0  = b * NP;
    const float4* P  = pts4 + bn0;         // raw (queries, fallback)
    const float4* S  = ptsS + bn0;         // pre-scaled (scan points)
    const float4* Pq = P + n0;             // this block's 32 queries

    for (int i = tid; i < KQ * 65; i += 512) skey[i] = 0xFFFFFFFFu;
    if (tid < KQ) scnt[tid] = 0;
    __syncthreads();

    const int base = w * 1024;             // wave's 1024-point range

    // ---- pass 1: two 512-pt segments; packed fma; min3-tree per segment ----
#pragma unroll 1
    for (int sg = 0; sg < 2; ++sg) {
        const int sb = base + sg * 512;
        f32x2 sx[4], sy[4], sz[4], sw2[4];
#pragma unroll
        for (int jp = 0; jp < 4; ++jp) {
            float4 a = S[sb + (2 * jp) * 64 + lane];
            float4 c = S[sb + (2 * jp + 1) * 64 + lane];
            sx[jp].x = a.x;  sx[jp].y = c.x;
            sy[jp].x = a.y;  sy[jp].y = c.y;
            sz[jp].x = a.z;  sz[jp].y = c.z;
            sw2[jp].x = a.w; sw2[jp].y = c.w;
        }
#pragma unroll 1
        for (int qc = 0; qc < 4; ++qc) {
            float4 qv[8];
#pragma unroll
            for (int i = 0; i < 8; ++i) qv[i] = Pq[qc * 8 + i];   // uniform -> s_load
#pragma unroll
            for (int i = 0; i < 8; ++i) {
                f32x2 qx, qy, qz;
                qx.x = qv[i].x; qx.y = qv[i].x;    // uniform -> SGPR pair
                qy.x = qv[i].y; qy.y = qv[i].y;
                qz.x = qv[i].z; qz.y = qv[i].z;
                f32x2 t0 = pk_fma(sz[0], qz, sw2[0]);
                f32x2 t1 = pk_fma(sz[1], qz, sw2[1]);
                f32x2 t2 = pk_fma(sz[2], qz, sw2[2]);
                f32x2 t3 = pk_fma(sz[3], qz, sw2[3]);
                t0 = pk_fma(sy[0], qy, t0);  t1 = pk_fma(sy[1], qy, t1);
                t2 = pk_fma(sy[2], qy, t2);  t3 = pk_fma(sy[3], qy, t3);
                t0 = pk_fma(sx[0], qx, t0);  t1 = pk_fma(sx[1], qx, t1);
                t2 = pk_fma(sx[2], qx, t2);  t3 = pk_fma(sx[3], qx, t3);
                float a  = fminf(fminf(t0.x, t0.y), t1.x);   // v_min3
                float b2 = fminf(fminf(t1.y, t2.x), t2.y);   // v_min3
                float c2 = fminf(fminf(t3.x, t3.y), a);      // v_min3
                float mn = fminf(b2, c2);
                atomicMin(&skey[(qc * 8 + i) * 65 + lane], fkey(mn));
            }
        }
    }
    __syncthreads();

    // ---- threshold: wave-parallel bitonic sort of the 64 class minima ----
#pragma unroll 1
    for (int qi = 0; qi < 4; ++qi) {
        const int q = w * 4 + qi;
        unsigned v = skey[q * 65 + lane];
#pragma unroll
        for (int k = 2; k <= 64; k <<= 1) {
#pragma unroll
            for (int j = k >> 1; j >= 1; j >>= 1) {
                unsigned o = xorswap(v, j);
                bool lower = (lane & j) == 0;
                bool up    = (lane & k) == 0;
                unsigned mn = umin_(v, o), mx = umax_(v, o);
                v = (lower == up) ? mn : mx;
            }
        }
        if (lane == 15) sT[q] = funkey(v);   // 16th smallest
    }
    __syncthreads();

    // ---- pass 2: bit-identical recompute (packed), per-point t<=T append ----
#pragma unroll 1
    for (int sg = 0; sg < 2; ++sg) {
        const int sb = base + sg * 512;
        f32x2 sx[4], sy[4], sz[4], sw2[4];
#pragma unroll
        for (int jp = 0; jp < 4; ++jp) {
            float4 a = S[sb + (2 * jp) * 64 + lane];
            float4 c = S[sb + (2 * jp + 1) * 64 + lane];
            sx[jp].x = a.x;  sx[jp].y = c.x;
            sy[jp].x = a.y;  sy[jp].y = c.y;
            sz[jp].x = a.z;  sz[jp].y = c.z;
            sw2[jp].x = a.w; sw2[jp].y = c.w;
        }
#pragma unroll 1
        for (int qc = 0; qc < 4; ++qc) {
            float4 qv[8];
#pragma unroll
            for (int i = 0; i < 8; ++i) qv[i] = Pq[qc * 8 + i];   // uniform -> s_load
#pragma unroll
            for (int i = 0; i < 8; ++i) {
                const int q = qc * 8 + i;
                const float T = sT[q];
                f32x2 qx, qy, qz;
                qx.x = qv[i].x; qx.y = qv[i].x;
                qy.x = qv[i].y; qy.y = qv[i].y;
                qz.x = qv[i].z; qz.y = qv[i].z;
#pragma unroll
                for (int jp = 0; jp < 4; ++jp) {
                    f32x2 t = pk_fma(sz[jp], qz, sw2[jp]);
                    t = pk_fma(sy[jp], qy, t);
                    t = pk_fma(sx[jp], qx, t);
                    if (t.x <= T) {
                        int pos = atomicAdd(&scnt[q], 1);
                        if (pos < CAP) {
                            cand_t[q * CSTR + pos] = t.x;
                            cand_i[q * CSTR + pos] = sb + (2 * jp) * 64 + lane;
                        }
                    }
                    if (t.y <= T) {
                        int pos = atomicAdd(&scnt[q], 1);
                        if (pos < CAP) {
                            cand_t[q * CSTR + pos] = t.y;
                            cand_i[q * CSTR + pos] = sb + (2 * jp + 1) * 64 + lane;
                        }
                    }
                }
            }
        }
    }
    __syncthreads();

    // ---- selection: wave-parallel bitonic over (fkey(d), idx) u64 keys ----
#pragma unroll 1
    for (int qi = 0; qi < 4; ++qi) {
        const int q = w * 4 + qi;
        const int cnt = scnt[q];
        int* outp = idxout + ((bn0 + n0 + q) << 4);
        if (cnt <= CAP) {
            unsigned kh = 0xFFFFFFFFu, kl = 0xFFFFFFFFu;
            if (lane < cnt) {
                kh = fkey(cand_t[q * CSTR + lane]);
                kl = (unsigned)cand_i[q * CSTR + lane];
            }
#pragma unroll
            for (int k = 2; k <= 64; k <<= 1) {
#pragma unroll
                for (int j = k >> 1; j >= 1; j >>= 1) {
                    unsigned oh = xorswap(kh, j);
                    unsigned ol = xorswap(kl, j);
                    bool lower = (lane & j) == 0;
                    bool up    = (lane & k) == 0;
                    bool lt    = (kh < oh) || (kh == oh && kl < ol);
                    bool keep  = ((lower == up) == lt);
                    kh = keep ? kh : oh;
                    kl = keep ? kl : ol;
                }
            }
            // extras 64..cnt-1 (<=16): ballot-ranked shift-insert, keeps order
            for (int e = 64; e < cnt; ++e) {
                unsigned eh = fkey(cand_t[q * CSTR + e]);
                unsigned el = (unsigned)cand_i[q * CSTR + e];
                unsigned long long less = __ballot((kh < eh) || (kh == eh && kl < el));
                int r = (int)__popcll(less);
                unsigned ph = __shfl_up(kh, 1);
                unsigned pl = __shfl_up(kl, 1);
                if (lane == r)      { kh = eh; kl = el; }
                else if (lane > r)  { kh = ph; kl = pl; }
            }
            if (lane < 16) outp[lane] = (int)kl;
        } else if (lane == 0) {
            // overflow fallback (exact, never expected): identical fma form
            float bd[16]; int bi[16];
#pragma unroll
            for (int i = 0; i < 16; ++i) { bd[i] = 3e38f; bi[i] = 0; }
            float4 q4 = Pq[q];
            for (int j = 0; j < NP; ++j) {
                float4 s = S[j];
                float d = fmaf(q4.x, s.x, fmaf(q4.y, s.y, fmaf(q4.z, s.z, s.w)));
                if ((d < bd[15]) || (d == bd[15] && j < bi[15])) {
                    bd[15] = d; bi[15] = j;
#pragma unroll
                    for (int i = 15; i > 0; --i) {
                        bool sw = (bd[i] < bd[i - 1]) || (bd[i] == bd[i - 1] && bi[i] < bi[i - 1]);
                        float td = bd[i - 1]; int tj = bi[i - 1];
                        bd[i - 1] = sw ? bd[i] : td;  bi[i - 1] = sw ? bi[i] : tj;
                        bd[i]     = sw ? td : bd[i];  bi[i]     = sw ? tj : bi[i];
                    }
                }
            }
#pragma unroll
            for (int i = 0; i < 16; ++i) outp[i] = bi[i];
        }
    }
}

// ---------------------------------------------------------------------------
// Kernel 3: gather + conv0 (f32) + conv1/conv2 MFMA hi/lo bf16 — session-best
// config unchanged (frag tables, g-major LDS, so-overlay, (256,4)).
// ---------------------------------------------------------------------------
__global__ __launch_bounds__(256, 4) void conv_kernel(
    const float4* __restrict__ pts4, const unsigned* __restrict__ featb,
    const int* __restrict__ idx, const float* __restrict__ W0,
    const uint4* __restrict__ w1f, const uint4* __restrict__ w2f,
    float* __restrict__ out)
{
    __shared__ __align__(16) unsigned short sh_hi[4][4][64][8];  // 16 KB
    __shared__ __align__(16) unsigned short sh_lo[4][4][64][8];  // 16 KB
    float* soF = (float*)&sh_lo[0][0][0][0];                     // overlay, 4.4 KB

    const int tid = threadIdx.x;
    const int w   = __builtin_amdgcn_readfirstlane(tid >> 6);  // wave 0..3
    const int l   = tid & 63;
    const int g   = l >> 4;                // k-group (A/B frag), 0..3
    const int q   = l & 15;                // spatial index (row of A / col of B)
    const int k   = tid & 15;              // neighbor index (== q)
    const int nl  = tid >> 4;              // 0..15 (== 4w+g)
    const int blk = blockIdx.x;            // 2048 blocks
    const int b   = blk >> 9;              // 512 blocks per batch
    const int n0  = (blk & 511) << 4;
    const int n   = n0 + nl;
    const int bn  = b * NP + n;
    const int j   = idx[(bn << 4) + k];
    const int bj  = b * NP + j;

    // ---- gather + conv0 (f32), split to hi/lo and stage (col = lane) ----
    const float4 pc = pts4[bn];
    const float4 pj = pts4[bj];
    const float rx = pj.x - pc.x, ry = pj.y - pc.y, rz = pj.z - pc.z;

    const uint4* fj = (const uint4*)(featb + (size_t)bj * 16);

#pragma unroll
    for (int gg = 0; gg < 4; ++gg) {
        uint4 u = fj[gg];
        const unsigned* uv = (const unsigned*)&u;
        uint4 hv, lv;
        unsigned* hp = (unsigned*)&hv;
        unsigned* lp = (unsigned*)&lv;
#pragma unroll
        for (int r = 0; r < 4; ++r) {
            int o = gg * 8 + 2 * r;
            float fe  = __uint_as_float(uv[r] << 16);
            float fo_ = __uint_as_float(uv[r] & 0xffff0000u);
            float e0 = lrelu(fmaf(W0[o * 35], rx, fmaf(W0[o * 35 + 1], ry, fmaf(W0[o * 35 + 2], rz, fe))));
            float e1 = lrelu(fmaf(W0[(o + 1) * 35], rx, fmaf(W0[(o + 1) * 35 + 1], ry, fmaf(W0[(o + 1) * 35 + 2], rz, fo_))));
            split_pack2(e0, e1, hp[r], lp[r]);
        }
        *(uint4*)&sh_hi[w][gg][l][0] = hv;
        *(uint4*)&sh_lo[w][gg][l][0] = lv;
    }

    // ---- conv1: B-frags from LDS (all loaded before any writeback) ----
    bf16x8 b1h[4], b1l[4];
#pragma unroll
    for (int t = 0; t < 4; ++t) {
        b1h[t] = *(const bf16x8*)&sh_hi[w][g][16 * t + q][0];
        b1l[t] = *(const bf16x8*)&sh_lo[w][g][16 * t + q][0];
    }
    const f32x4 zz = {0.f, 0.f, 0.f, 0.f};
#pragma unroll
    for (int r = 0; r < 2; ++r) {
        bf16x8 wh = *(const bf16x8*)&w1f[(r * 64 + l) * 2 + 0];
        bf16x8 wl = *(const bf16x8*)&w1f[(r * 64 + l) * 2 + 1];
#pragma unroll
        for (int t = 0; t < 4; ++t) {
            f32x4 a = mfma16(wl, b1h[t], zz);
            a = mfma16(wh, b1l[t], a);
            a = mfma16(wh, b1h[t], a);
            // x1 rows o1 = 16r+4g+{0..3}, col 16t+q -> k-group (16r+4g)>>3
            float v0 = lrelu(a[0]);
            float v1 = lrelu(a[1]);
            float v2 = lrelu(a[2]);
            float v3 = lrelu(a[3]);
            uint2 hv, lv;
            split_pack2(v0, v1, hv.x, lv.x);
            split_pack2(v2, v3, hv.y, lv.y);
            const int kg = 2 * r + (g >> 1);
            const int ko = 4 * (g & 1);
            *(uint2*)&sh_hi[w][kg][16 * t + q][ko] = hv;
            *(uint2*)&sh_lo[w][kg][16 * t + q][ko] = lv;
        }
    }

    // ---- conv2 (swapped operands): load ALL x1 frags, then barrier so the
    //      so-overlay (in sh_lo) can be written safely by every wave ----
    bf16x8 b2h[4], b2l[4];
#pragma unroll
    for (int t = 0; t < 4; ++t) {
        b2h[t] = *(const bf16x8*)&sh_hi[w][g][16 * t + q][0];
        b2l[t] = *(const bf16x8*)&sh_lo[w][g][16 * t + q][0];
    }
    __syncthreads();   // all sh_lo reads complete before so writes begin

#pragma unroll
    for (int rr = 0; rr < 4; ++rr) {
        bf16x8 wh = *(const bf16x8*)&w2f[(rr * 64 + l) * 2 + 0];
        bf16x8 wl = *(const bf16x8*)&w2f[(rr * 64 + l) * 2 + 1];
#pragma unroll
        for (int t = 0; t < 4; ++t) {
            f32x4 a = mfma16(b2h[t], wl, zz);
            a = mfma16(b2l[t], wh, a);
            a = mfma16(b2h[t], wh, a);
            // lane holds o = 16rr+q (D col), k = 4g+{0..3} (D rows), n = n0+4w+t
            float m = fmaxf(fmaxf(a[0], a[1]), fmaxf(a[2], a[3]));
            m = fmaxf(m, __int_as_float(__builtin_amdgcn_ds_swizzle(__float_as_int(m), 0x401F)));  // g^1
            m = fmaxf(m, __shfl_xor(m, 32));                                                       // g^2
            if (g == 0) soF[(16 * rr + q) * 17 + w * 4 + t] = lrelu(m);
        }
    }
    __syncthreads();
    {
        int o = tid >> 2;                 // 0..63
        int col = (tid & 3) << 2;         // 0,4,8,12
        float4 v = make_float4(soF[o * 17 + col], soF[o * 17 + col + 1],
                               soF[o * 17 + col + 2], soF[o * 17 + col + 3]);
        *(float4*)(out + ((size_t)(b * M2 + o)) * NP + n0 + col) = v;
    }
}

// ---------------------------------------------------------------------------
extern "C" void kernel_launch(void* const* d_in, const int* in_sizes, int n_in,
                              void* d_out, int out_size, void* d_ws, size_t ws_size,
                              hipStream_t stream)
{
    const float* xyz    = (const float*)d_in[0];
    const float* points = (const float*)d_in[1];
    const float* W0     = (const float*)d_in[2];
    const float* W1     = (const float*)d_in[3];
    const float* W2     = (const float*)d_in[4];
    float* out = (float*)d_out;

    char* ws = (char*)d_ws;
    float4*   pts4  = (float4*)ws;                       // 512 KB
    float4*   ptsS  = (float4*)(ws + 0x080000);          // 512 KB (pre-scaled)
    unsigned* featb = (unsigned*)(ws + 0x100000);        // 2 MB
    int*      idx   = (int*)(ws + 0x300000);             // 2 MB
    uint4*    w1f   = (uint4*)(ws + 0x500000);           // 4 KB frag table
    uint4*    w2f   = (uint4*)(ws + 0x502000);           // 8 KB frag table

    prep_kernel<<<BB * NP / 64, 256,  0, stream>>>(xyz, points, W0, W1, W2, pts4, ptsS, featb, w1f, w2f);
    knn_kernel <<<BB * NP / KQ, 512,  0, stream>>>(pts4, ptsS, idx);
    conv_kernel<<<BB * NP / 16, 256,  0, stream>>>(pts4, featb, idx, W0, w1f, w2f, out);
}

// Round 12
// 171.313 us; speedup vs baseline: 1.0235x; 1.0235x over previous
//
#include <hip/hip_runtime.h>

#define NP   8192
#define BB   4
#define DIN  32
#define M0   32
#define M1   32
#define M2   64
#define CAP  80
#define CSTR 81            // candidate row stride (odd -> conflict-free)
#define KQ   32            // queries per knn block

typedef float f32x2 __attribute__((ext_vector_type(2)));
typedef float f32x4 __attribute__((ext_vector_type(4)));
typedef short bf16x8 __attribute__((ext_vector_type(8)));

__device__ __forceinline__ float lrelu(float x) { return fmaxf(x, 0.1f * x); }
__device__ __forceinline__ unsigned umin_(unsigned a, unsigned b) { return a < b ? a : b; }
__device__ __forceinline__ unsigned umax_(unsigned a, unsigned b) { return a > b ? a : b; }

// monotonic float->uint key (total order incl. negatives)
__device__ __forceinline__ unsigned fkey(float f) {
    unsigned b = __float_as_uint(f);
    return (b & 0x80000000u) ? ~b : (b | 0x80000000u);
}
__device__ __forceinline__ float funkey(unsigned k) {
    unsigned b = (k & 0x80000000u) ? (k & 0x7fffffffu) : ~k;
    return __uint_as_float(b);
}

// round-to-nearest-even f32 -> bf16 (as uint16 in low bits)
__device__ __forceinline__ unsigned bf16rn(float f) {
    unsigned u = __float_as_uint(f);
    unsigned r = (u >> 16) & 1u;
    return (u + 0x7fffu + r) >> 16;
}

// packed f32 FMA (knn): d = a*b + c per half; b wave-uniform -> SGPR pair.
__device__ __forceinline__ f32x2 pk_fma(f32x2 a, f32x2 b, f32x2 c) {
    f32x2 d;
    asm("v_pk_fma_f32 %0, %1, %2, %3" : "=v"(d) : "v"(a), "s"(b), "v"(c));
    return d;
}

// exact lane^j exchange, cheapest primitive per stride. All three forms are
// already proven in this kernel (conv: DPP 0xB1/0x4E, ds_swizzle 0x401F).
// j folds to a constant under full unroll -> each case uses a literal pattern.
__device__ __forceinline__ unsigned xorswap(unsigned v, int j) {
    switch (j) {
    case 1:  return (unsigned)__builtin_amdgcn_update_dpp(0, (int)v, 0xB1, 0xf, 0xf, true); // quad xor1
    case 2:  return (unsigned)__builtin_amdgcn_update_dpp(0, (int)v, 0x4E, 0xf, 0xf, true); // quad xor2
    case 4:  return (unsigned)__builtin_amdgcn_ds_swizzle((int)v, 0x101F);  // BitMode xor4
    case 8:  return (unsigned)__builtin_amdgcn_ds_swizzle((int)v, 0x201F);  // BitMode xor8
    case 16: return (unsigned)__builtin_amdgcn_ds_swizzle((int)v, 0x401F);  // BitMode xor16
    default: return (unsigned)__shfl_xor((int)v, 32);                       // crosses 32-lane half
    }
}

// hi/lo bf16 split of a float pair, packed as two u32 (lo16|hi16 each).
__device__ __forceinline__ void split_pack2(float f0, float f1, unsigned& hp, unsigned& lp) {
    unsigned u0 = __float_as_uint(f0), u1 = __float_as_uint(f1);
    unsigned h0 = u0 & 0xffff0000u, h1 = u1 & 0xffff0000u;
    hp = (u0 >> 16) | h1;
    float r0 = f0 - __uint_as_float(h0);
    float r1 = f1 - __uint_as_float(h1);
    lp = (__float_as_uint(r0) >> 16) | (__float_as_uint(r1) & 0xffff0000u);
}

// Build hi/lo bf16 A/B-fragments from 8 consecutive f32 weights.
__device__ __forceinline__ void wfrag(const float* wrow, bf16x8& h, bf16x8& lo) {
    float4 a = *(const float4*)(wrow);
    float4 b = *(const float4*)(wrow + 4);
    unsigned* hv = (unsigned*)&h;
    unsigned* lv = (unsigned*)&lo;
    split_pack2(a.x, a.y, hv[0], lv[0]);
    split_pack2(a.z, a.w, hv[1], lv[1]);
    split_pack2(b.x, b.y, hv[2], lv[2]);
    split_pack2(b.z, b.w, hv[3], lv[3]);
}

__device__ __forceinline__ f32x4 mfma16(bf16x8 a, bf16x8 b, f32x4 c) {
    return __builtin_amdgcn_mfma_f32_16x16x32_bf16(a, b, c, 0, 0, 0);
}

// ---------------------------------------------------------------------------
// Kernel 1: pack pts4/ptsS + feat = W0[:,3:] @ points (bf16 pairs). Block 0
// additionally writes the per-lane W1/W2 hi/lo MFMA fragment tables.
// ---------------------------------------------------------------------------
__global__ __launch_bounds__(256) void prep_kernel(
    const float* __restrict__ xyz, const float* __restrict__ points,
    const float* __restrict__ W0, const float* __restrict__ W1,
    const float* __restrict__ W2, float4* __restrict__ pts4,
    float4* __restrict__ ptsS, unsigned* __restrict__ featb,
    uint4* __restrict__ w1f, uint4* __restrict__ w2f)
{
    const int tid  = threadIdx.x;
    const int w    = __builtin_amdgcn_readfirstlane(tid >> 6);  // 0..3
    const int lane = tid & 63;
    const int t    = blockIdx.x * 64 + lane;     // point id, 512 blocks
    const int b    = t >> 13;
    const int n    = t & (NP - 1);

    if (w == 0) {
        const float* xb = xyz + (size_t)b * 3 * NP;
        float x = xb[n], y = xb[NP + n], z = xb[2 * NP + n];
        float s = x * x + y * y + z * z;
        pts4[t] = make_float4(x, y, z, s);
        ptsS[t] = make_float4(-2.f * x, -2.f * y, -2.f * z, s);
    }

    const float* pb = points + (size_t)b * DIN * NP + n;
    float p[DIN];
#pragma unroll
    for (int c = 0; c < DIN; ++c) p[c] = pb[c * NP];

    uint4 outv;
    unsigned* ov = (unsigned*)&outv;
#pragma unroll
    for (int r = 0; r < 4; ++r) {
        int oe = w * 8 + 2 * r;
        float a0 = 0.f, a1 = 0.f;
#pragma unroll
        for (int c = 0; c < DIN; ++c) {
            a0 = fmaf(W0[oe * 35 + 3 + c], p[c], a0);
            a1 = fmaf(W0[(oe + 1) * 35 + 3 + c], p[c], a1);
        }
        ov[r] = bf16rn(a0) | (bf16rn(a1) << 16);
    }
    *(uint4*)(featb + (size_t)t * 16 + w * 4) = outv;

    // ---- one-time W fragment tables (lane l: q=l&15 spatial, g=l>>4 kgrp) ----
    if (blockIdx.x == 0 && tid < 64) {
        const int qq = tid & 15, gg = tid >> 4;
        bf16x8 h, lo;
#pragma unroll
        for (int r = 0; r < 2; ++r) {
            wfrag(W1 + (16 * r + qq) * 32 + gg * 8, h, lo);
            w1f[(r * 64 + tid) * 2 + 0] = *(uint4*)&h;
            w1f[(r * 64 + tid) * 2 + 1] = *(uint4*)&lo;
        }
#pragma unroll
        for (int rr = 0; rr < 4; ++rr) {
            wfrag(W2 + (16 * rr + qq) * 32 + gg * 8, h, lo);
            w2f[(rr * 64 + tid) * 2 + 0] = *(uint4*)&h;
            w2f[(rr * 64 + tid) * 2 + 1] = *(uint4*)&lo;
        }
    }
}

// ---------------------------------------------------------------------------
// Kernel 2: exact 16-NN — session-best (measured 92.6 µs): 512-thr blocks,
// 32 queries each, wave-parallel bitonic threshold/selection with
// DPP/ds_swizzle/shfl lane exchanges (xorswap), per-half atomic appends.
// ---------------------------------------------------------------------------
__global__ __launch_bounds__(512, 8) void knn_kernel(const float4* __restrict__ pts4,
                                                     const float4* __restrict__ ptsS,
                                                     int* __restrict__ idxout)
{
    __shared__ unsigned skey[KQ * 65];              // 8.3 KB class-min keys
    __shared__ float    sT[KQ];
    __shared__ int      scnt[KQ];
    __shared__ float    cand_t[KQ * CSTR];          // 10.4 KB
    __shared__ int      cand_i[KQ * CSTR];          // 10.4 KB

    const int tid  = threadIdx.x;
    const int w    = __builtin_amdgcn_readfirstlane(tid >> 6);   // 0..7
    const int lane = tid & 63;
    const int blk  = blockIdx.x;           // 1024 blocks
    const int b    = blk >> 8;
    const int n0   = (blk & 255) << 5;     // 32 queries per block
    const int bn0  = b * NP;
    const float4* P  = pts4 + bn0;         // raw (queries, fallback)
    const float4* S  = ptsS + bn0;         // pre-scaled (scan points)
    const float4* Pq = P + n0;             // this block's 32 queries

    for (int i = tid; i < KQ * 65; i += 512) skey[i] = 0xFFFFFFFFu;
    if (tid < KQ) scnt[tid] = 0;
    __syncthreads();

    const int base = w * 1024;             // wave's 1024-point range

    // ---- pass 1: two 512-pt segments; packed fma; min3-tree per segment ----
#pragma unroll 1
    for (int sg = 0; sg < 2; ++sg) {
        const int sb = base + sg * 512;
        f32x2 sx[4], sy[4], sz[4], sw2[4];
#pragma unroll
        for (int jp = 0; jp < 4; ++jp) {
            float4 a = S[sb + (2 * jp) * 64 + lane];
            float4 c = S[sb + (2 * jp + 1) * 64 + lane];
            sx[jp].x = a.x;  sx[jp].y = c.x;
            sy[jp].x = a.y;  sy[jp].y = c.y;
            sz[jp].x = a.z;  sz[jp].y = c.z;
            sw2[jp].x = a.w; sw2[jp].y = c.w;
        }
#pragma unroll 1
        for (int qc = 0; qc < 4; ++qc) {
            float4 qv[8];
#pragma unroll
            for (int i = 0; i < 8; ++i) qv[i] = Pq[qc * 8 + i];   // uniform -> s_load
#pragma unroll
            for (int i = 0; i < 8; ++i) {
                f32x2 qx, qy, qz;
                qx.x = qv[i].x; qx.y = qv[i].x;    // uniform -> SGPR pair
                qy.x = qv[i].y; qy.y = qv[i].y;
                qz.x = qv[i].z; qz.y = qv[i].z;
                f32x2 t0 = pk_fma(sz[0], qz, sw2[0]);
                f32x2 t1 = pk_fma(sz[1], qz, sw2[1]);
                f32x2 t2 = pk_fma(sz[2], qz, sw2[2]);
                f32x2 t3 = pk_fma(sz[3], qz, sw2[3]);
                t0 = pk_fma(sy[0], qy, t0);  t1 = pk_fma(sy[1], qy, t1);
                t2 = pk_fma(sy[2], qy, t2);  t3 = pk_fma(sy[3], qy, t3);
                t0 = pk_fma(sx[0], qx, t0);  t1 = pk_fma(sx[1], qx, t1);
                t2 = pk_fma(sx[2], qx, t2);  t3 = pk_fma(sx[3], qx, t3);
                float a  = fminf(fminf(t0.x, t0.y), t1.x);   // v_min3
                float b2 = fminf(fminf(t1.y, t2.x), t2.y);   // v_min3
                float c2 = fminf(fminf(t3.x, t3.y), a);      // v_min3
                float mn = fminf(b2, c2);
                atomicMin(&skey[(qc * 8 + i) * 65 + lane], fkey(mn));
            }
        }
    }
    __syncthreads();

    // ---- threshold: wave-parallel bitonic sort of the 64 class minima ----
#pragma unroll 1
    for (int qi = 0; qi < 4; ++qi) {
        const int q = w * 4 + qi;
        unsigned v = skey[q * 65 + lane];
#pragma unroll
        for (int k = 2; k <= 64; k <<= 1) {
#pragma unroll
            for (int j = k >> 1; j >= 1; j >>= 1) {
                unsigned o = xorswap(v, j);
                bool lower = (lane & j) == 0;
                bool up    = (lane & k) == 0;
                unsigned mn = umin_(v, o), mx = umax_(v, o);
                v = (lower == up) ? mn : mx;
            }
        }
        if (lane == 15) sT[q] = funkey(v);   // 16th smallest
    }
    __syncthreads();

    // ---- pass 2: bit-identical recompute (packed), per-point t<=T append ----
#pragma unroll 1
    for (int sg = 0; sg < 2; ++sg) {
        const int sb = base + sg * 512;
        f32x2 sx[4], sy[4], sz[4], sw2[4];
#pragma unroll
        for (int jp = 0; jp < 4; ++jp) {
            float4 a = S[sb + (2 * jp) * 64 + lane];
            float4 c = S[sb + (2 * jp + 1) * 64 + lane];
            sx[jp].x = a.x;  sx[jp].y = c.x;
            sy[jp].x = a.y;  sy[jp].y = c.y;
            sz[jp].x = a.z;  sz[jp].y = c.z;
            sw2[jp].x = a.w; sw2[jp].y = c.w;
        }
#pragma unroll 1
        for (int qc = 0; qc < 4; ++qc) {
            float4 qv[8];
#pragma unroll
            for (int i = 0; i < 8; ++i) qv[i] = Pq[qc * 8 + i];   // uniform -> s_load
#pragma unroll
            for (int i = 0; i < 8; ++i) {
                const int q = qc * 8 + i;
                const float T = sT[q];
                f32x2 qx, qy, qz;
                qx.x = qv[i].x; qx.y = qv[i].x;
                qy.x = qv[i].y; qy.y = qv[i].y;
                qz.x = qv[i].z; qz.y = qv[i].z;
#pragma unroll
                for (int jp = 0; jp < 4; ++jp) {
                    f32x2 t = pk_fma(sz[jp], qz, sw2[jp]);
                    t = pk_fma(sy[jp], qy, t);
                    t = pk_fma(sx[jp], qx, t);
                    if (t.x <= T) {
                        int pos = atomicAdd(&scnt[q], 1);
                        if (pos < CAP) {
                            cand_t[q * CSTR + pos] = t.x;
                            cand_i[q * CSTR + pos] = sb + (2 * jp) * 64 + lane;
                        }
                    }
                    if (t.y <= T) {
                        int pos = atomicAdd(&scnt[q], 1);
                        if (pos < CAP) {
                            cand_t[q * CSTR + pos] = t.y;
                            cand_i[q * CSTR + pos] = sb + (2 * jp + 1) * 64 + lane;
                        }
                    }
                }
            }
        }
    }
    __syncthreads();

    // ---- selection: wave-parallel bitonic over (fkey(d), idx) u64 keys ----
#pragma unroll 1
    for (int qi = 0; qi < 4; ++qi) {
        const int q = w * 4 + qi;
        const int cnt = scnt[q];
        int* outp = idxout + ((bn0 + n0 + q) << 4);
        if (cnt <= CAP) {
            unsigned kh = 0xFFFFFFFFu, kl = 0xFFFFFFFFu;
            if (lane < cnt) {
                kh = fkey(cand_t[q * CSTR + lane]);
                kl = (unsigned)cand_i[q * CSTR + lane];
            }
#pragma unroll
            for (int k = 2; k <= 64; k <<= 1) {
#pragma unroll
                for (int j = k >> 1; j >= 1; j >>= 1) {
                    unsigned oh = xorswap(kh, j);
                    unsigned ol = xorswap(kl, j);
                    bool lower = (lane & j) == 0;
                    bool up    = (lane & k) == 0;
                    bool lt    = (kh < oh) || (kh == oh && kl < ol);
                    bool keep  = ((lower == up) == lt);
                    kh = keep ? kh : oh;
                    kl = keep ? kl : ol;
                }
            }
            // extras 64..cnt-1 (<=16): ballot-ranked shift-insert, keeps order
            for (int e = 64; e < cnt; ++e) {
                unsigned eh = fkey(cand_t[q * CSTR + e]);
                unsigned el = (unsigned)cand_i[q * CSTR + e];
                unsigned long long less = __ballot((kh < eh) || (kh == eh && kl < el));
                int r = (int)__popcll(less);
                unsigned ph = __shfl_up(kh, 1);
                unsigned pl = __shfl_up(kl, 1);
                if (lane == r)      { kh = eh; kl = el; }
                else if (lane > r)  { kh = ph; kl = pl; }
            }
            if (lane < 16) outp[lane] = (int)kl;
        } else if (lane == 0) {
            // overflow fallback (exact, never expected): identical fma form
            float bd[16]; int bi[16];
#pragma unroll
            for (int i = 0; i < 16; ++i) { bd[i] = 3e38f; bi[i] = 0; }
            float4 q4 = Pq[q];
            for (int j = 0; j < NP; ++j) {
                float4 s = S[j];
                float d = fmaf(q4.x, s.x, fmaf(q4.y, s.y, fmaf(q4.z, s.z, s.w)));
                if ((d < bd[15]) || (d == bd[15] && j < bi[15])) {
                    bd[15] = d; bi[15] = j;
#pragma unroll
                    for (int i = 15; i > 0; --i) {
                        bool sw = (bd[i] < bd[i - 1]) || (bd[i] == bd[i - 1] && bi[i] < bi[i - 1]);
                        float td = bd[i - 1]; int tj = bi[i - 1];
                        bd[i - 1] = sw ? bd[i] : td;  bi[i - 1] = sw ? bi[i] : tj;
                        bd[i]     = sw ? td : bd[i];  bi[i]     = sw ? tj : bi[i];
                    }
                }
            }
#pragma unroll
            for (int i = 0; i < 16; ++i) outp[i] = bi[i];
        }
    }
}

// ---------------------------------------------------------------------------
// Kernel 3: gather + conv0 (f32) + conv1/conv2 MFMA hi/lo bf16 — session-best
// config unchanged (frag tables, g-major LDS, so-overlay, (256,4)).
// ---------------------------------------------------------------------------
__global__ __launch_bounds__(256, 4) void conv_kernel(
    const float4* __restrict__ pts4, const unsigned* __restrict__ featb,
    const int* __restrict__ idx, const float* __restrict__ W0,
    const uint4* __restrict__ w1f, const uint4* __restrict__ w2f,
    float* __restrict__ out)
{
    __shared__ __align__(16) unsigned short sh_hi[4][4][64][8];  // 16 KB
    __shared__ __align__(16) unsigned short sh_lo[4][4][64][8];  // 16 KB
    float* soF = (float*)&sh_lo[0][0][0][0];                     // overlay, 4.4 KB

    const int tid = threadIdx.x;
    const int w   = __builtin_amdgcn_readfirstlane(tid >> 6);  // wave 0..3
    const int l   = tid & 63;
    const int g   = l >> 4;                // k-group (A/B frag), 0..3
    const int q   = l & 15;                // spatial index (row of A / col of B)
    const int k   = tid & 15;              // neighbor index (== q)
    const int nl  = tid >> 4;              // 0..15 (== 4w+g)
    const int blk = blockIdx.x;            // 2048 blocks
    const int b   = blk >> 9;              // 512 blocks per batch
    const int n0  = (blk & 511) << 4;
    const int n   = n0 + nl;
    const int bn  = b * NP + n;
    const int j   = idx[(bn << 4) + k];
    const int bj  = b * NP + j;

    // ---- gather + conv0 (f32), split to hi/lo and stage (col = lane) ----
    const float4 pc = pts4[bn];
    const float4 pj = pts4[bj];
    const float rx = pj.x - pc.x, ry = pj.y - pc.y, rz = pj.z - pc.z;

    const uint4* fj = (const uint4*)(featb + (size_t)bj * 16);

#pragma unroll
    for (int gg = 0; gg < 4; ++gg) {
        uint4 u = fj[gg];
        const unsigned* uv = (const unsigned*)&u;
        uint4 hv, lv;
        unsigned* hp = (unsigned*)&hv;
        unsigned* lp = (unsigned*)&lv;
#pragma unroll
        for (int r = 0; r < 4; ++r) {
            int o = gg * 8 + 2 * r;
            float fe  = __uint_as_float(uv[r] << 16);
            float fo_ = __uint_as_float(uv[r] & 0xffff0000u);
            float e0 = lrelu(fmaf(W0[o * 35], rx, fmaf(W0[o * 35 + 1], ry, fmaf(W0[o * 35 + 2], rz, fe))));
            float e1 = lrelu(fmaf(W0[(o + 1) * 35], rx, fmaf(W0[(o + 1) * 35 + 1], ry, fmaf(W0[(o + 1) * 35 + 2], rz, fo_))));
            split_pack2(e0, e1, hp[r], lp[r]);
        }
        *(uint4*)&sh_hi[w][gg][l][0] = hv;
        *(uint4*)&sh_lo[w][gg][l][0] = lv;
    }

    // ---- conv1: B-frags from LDS (all loaded before any writeback) ----
    bf16x8 b1h[4], b1l[4];
#pragma unroll
    for (int t = 0; t < 4; ++t) {
        b1h[t] = *(const bf16x8*)&sh_hi[w][g][16 * t + q][0];
        b1l[t] = *(const bf16x8*)&sh_lo[w][g][16 * t + q][0];
    }
    const f32x4 zz = {0.f, 0.f, 0.f, 0.f};
#pragma unroll
    for (int r = 0; r < 2; ++r) {
        bf16x8 wh = *(const bf16x8*)&w1f[(r * 64 + l) * 2 + 0];
        bf16x8 wl = *(const bf16x8*)&w1f[(r * 64 + l) * 2 + 1];
#pragma unroll
        for (int t = 0; t < 4; ++t) {
            f32x4 a = mfma16(wl, b1h[t], zz);
            a = mfma16(wh, b1l[t], a);
            a = mfma16(wh, b1h[t], a);
            // x1 rows o1 = 16r+4g+{0..3}, col 16t+q -> k-group (16r+4g)>>3
            float v0 = lrelu(a[0]);
            float v1 = lrelu(a[1]);
            float v2 = lrelu(a[2]);
            float v3 = lrelu(a[3]);
            uint2 hv, lv;
            split_pack2(v0, v1, hv.x, lv.x);
            split_pack2(v2, v3, hv.y, lv.y);
            const int kg = 2 * r + (g >> 1);
            const int ko = 4 * (g & 1);
            *(uint2*)&sh_hi[w][kg][16 * t + q][ko] = hv;
            *(uint2*)&sh_lo[w][kg][16 * t + q][ko] = lv;
        }
    }

    // ---- conv2 (swapped operands): load ALL x1 frags, then barrier so the
    //      so-overlay (in sh_lo) can be written safely by every wave ----
    bf16x8 b2h[4], b2l[4];
#pragma unroll
    for (int t = 0; t < 4; ++t) {
        b2h[t] = *(const bf16x8*)&sh_hi[w][g][16 * t + q][0];
        b2l[t] = *(const bf16x8*)&sh_lo[w][g][16 * t + q][0];
    }
    __syncthreads();   // all sh_lo reads complete before so writes begin

#pragma unroll
    for (int rr = 0; rr < 4; ++rr) {
        bf16x8 wh = *(const bf16x8*)&w2f[(rr * 64 + l) * 2 + 0];
        bf16x8 wl = *(const bf16x8*)&w2f[(rr * 64 + l) * 2 + 1];
#pragma unroll
        for (int t = 0; t < 4; ++t) {
            f32x4 a = mfma16(b2h[t], wl, zz);
            a = mfma16(b2l[t], wh, a);
            a = mfma16(b2h[t], wh, a);
            // lane holds o = 16rr+q (D col), k = 4g+{0..3} (D rows), n = n0+4w+t
            float m = fmaxf(fmaxf(a[0], a[1]), fmaxf(a[2], a[3]));
            m = fmaxf(m, __int_as_float(__builtin_amdgcn_ds_swizzle(__float_as_int(m), 0x401F)));  // g^1
            m = fmaxf(m, __shfl_xor(m, 32));                                                       // g^2
            if (g == 0) soF[(16 * rr + q) * 17 + w * 4 + t] = lrelu(m);
        }
    }
    __syncthreads();
    {
        int o = tid >> 2;                 // 0..63
        int col = (tid & 3) << 2;         // 0,4,8,12
        float4 v = make_float4(soF[o * 17 + col], soF[o * 17 + col + 1],
                               soF[o * 17 + col + 2], soF[o * 17 + col + 3]);
        *(float4*)(out + ((size_t)(b * M2 + o)) * NP + n0 + col) = v;
    }
}

// ---------------------------------------------------------------------------
extern "C" void kernel_launch(void* const* d_in, const int* in_sizes, int n_in,
                              void* d_out, int out_size, void* d_ws, size_t ws_size,
                              hipStream_t stream)
{
    const float* xyz    = (const float*)d_in[0];
    const float* points = (const float*)d_in[1];
    const float* W0     = (const float*)d_in[2];
    const float* W1     = (const float*)d_in[3];
    const float* W2     = (const float*)d_in[4];
    float* out = (float*)d_out;

    char* ws = (char*)d_ws;
    float4*   pts4  = (float4*)ws;                       // 512 KB
    float4*   ptsS  = (float4*)(ws + 0x080000);          // 512 KB (pre-scaled)
    unsigned* featb = (unsigned*)(ws + 0x100000);        // 2 MB
    int*      idx   = (int*)(ws + 0x300000);             // 2 MB
    uint4*    w1f   = (uint4*)(ws + 0x500000);           // 4 KB frag table
    uint4*    w2f   = (uint4*)(ws + 0x502000);           // 8 KB frag table

    prep_kernel<<<BB * NP / 64, 256,  0, stream>>>(xyz, points, W0, W1, W2, pts4, ptsS, featb, w1f, w2f);
    knn_kernel <<<BB * NP / KQ, 512,  0, stream>>>(pts4, ptsS, idx);
    conv_kernel<<<BB * NP / 16, 256,  0, stream>>>(pts4, featb, idx, W0, w1f, w2f, out);
}